// Round 19
// baseline (196.288 us; speedup 1.0000x reference)
//
#include <hip/hip_runtime.h>

typedef __attribute__((ext_vector_type(8))) short sh8;
typedef __attribute__((ext_vector_type(8))) __bf16 bf8v;
typedef __attribute__((ext_vector_type(4))) float f4v;
typedef __attribute__((ext_vector_type(16))) float f16v;
typedef __attribute__((ext_vector_type(4))) unsigned u4v;

__device__ __forceinline__ float fast_exp2(float x) { return __builtin_amdgcn_exp2f(x); }

__device__ __forceinline__ unsigned short f2bf(float f) {
  unsigned u = __builtin_bit_cast(unsigned, f);
  u += 0x7fffu + ((u >> 16) & 1u);
  return (unsigned short)(u >> 16);
}
__device__ __forceinline__ float bf2f(unsigned short h) {
  unsigned u = ((unsigned)h) << 16;
  return __builtin_bit_cast(float, u);
}

// async global->LDS, 16B per lane; LDS dest = wave-uniform base + lane*16
__device__ __forceinline__ void glds16(const unsigned short* g, unsigned short* l) {
  __builtin_amdgcn_global_load_lds((const __attribute__((address_space(1))) void*)g,
                                   (__attribute__((address_space(3))) void*)l, 16, 0, 0);
}

// ---------------- cast x -> bf16 (vectorized) ----------------
__global__ __launch_bounds__(256) void cast_kernel(const float* __restrict__ in,
                                                   unsigned short* __restrict__ out) {
  const int idx = (blockIdx.x * 256 + threadIdx.x) * 4;
  const float4 v = *(const float4*)(in + idx);
  ushort4 o;
  o.x = f2bf(v.x); o.y = f2bf(v.y); o.z = f2bf(v.z); o.w = f2bf(v.w);
  *(ushort4*)(out + idx) = o;
}

// ---------------- transpose + cast weights: in[R][C] -> out[C][R] bf16 ----------------
__global__ __launch_bounds__(256) void transpose_cast_kernel(const float* __restrict__ in,
                                                             unsigned short* __restrict__ out,
                                                             int R, int C) {
  __shared__ float tile[32][33];
  const int c0 = blockIdx.x * 32, r0 = blockIdx.y * 32;
  const int tx = threadIdx.x, ty = threadIdx.y;
#pragma unroll
  for (int i = 0; i < 4; ++i)
    tile[ty + 8 * i][tx] = in[(size_t)(r0 + ty + 8 * i) * C + c0 + tx];
  __syncthreads();
#pragma unroll
  for (int i = 0; i < 4; ++i)
    out[(size_t)(c0 + ty + 8 * i) * R + r0 + tx] = f2bf(tile[tx][ty + 8 * i]);
}

// ------- bf16 MFMA GEMM with per-MODE loop structure (byte-identical to r18):
// MODE 0 (QKV): m97 single-buffer loop, BK=64 (32 KB LDS, 4 blocks/CU).
//   Q/K: direct contiguous stores; V: LDS-bounce transpose -> vt[bh][64][2048].
// MODE 1 (proj, 512 blocks): r7 4-deep issue-before-barrier counted-vmcnt pipeline (BK=32).
template <int MODE>
__global__ __launch_bounds__(256, MODE == 0 ? 4 : 2) void gemm_bf16_kernel(
    const unsigned short* __restrict__ A,
    const unsigned short* __restrict__ Bt,
    int M, int N, int K,
    unsigned short* __restrict__ q_out, unsigned short* __restrict__ k_out,
    unsigned short* __restrict__ v_out,
    const float* __restrict__ bias, float* __restrict__ c_out) {
  constexpr int SMEM_SH = (MODE == 0) ? (128 * 128) : (2 * 4 * 128 * 32);
  __shared__ alignas(16) unsigned short smem[SMEM_SH];
  const int tid = threadIdx.x;
  const int lane = tid & 63;
  const int wave = tid >> 6;
  const int wr = (wave >> 1) * 64;
  const int wc = (wave & 1) * 64;
  const int bm = blockIdx.x * 128;
  const int bn = blockIdx.y * 128;
  const int fr = lane & 15;
  const int kq = lane >> 4;

  f4v acc[4][4] = {};

  if constexpr (MODE == 0) {
    // ---- m97 single-buffer loop, BK=64 ----
    unsigned short* As = smem;          // [128][64]
    unsigned short* Bs = smem + 8192;   // [128][64]
    const int srow = lane >> 3;                 // 0..7
    const int sslot = (lane & 7) ^ srow;        // pre-swizzled source slot (row&7 == srow)
    const int nT = K >> 6;                      // 16 for K=1024
    for (int j = 0; j < nT; ++j) {
      const int k0 = j * 64;
      __syncthreads();
#pragma unroll
      for (int c = 0; c < 4; ++c) {
        const int rowbase = wave * 32 + c * 8;
        glds16(&A[(size_t)(bm + rowbase + srow) * K + k0 + sslot * 8], &As[rowbase * 64]);
        glds16(&Bt[(size_t)(bn + rowbase + srow) * K + k0 + sslot * 8], &Bs[rowbase * 64]);
      }
      __syncthreads();

#pragma unroll
      for (int h = 0; h < 2; ++h) {
        bf8v af[4], bfv[4];
        const int rsl = (((h << 2) | kq) ^ (fr & 7)) * 8;
#pragma unroll
        for (int m = 0; m < 4; ++m)
          af[m] = __builtin_bit_cast(bf8v, *(const sh8*)&As[(wr + m * 16 + fr) * 64 + rsl]);
#pragma unroll
        for (int n = 0; n < 4; ++n)
          bfv[n] = __builtin_bit_cast(bf8v, *(const sh8*)&Bs[(wc + n * 16 + fr) * 64 + rsl]);
        __builtin_amdgcn_s_setprio(1);
#pragma unroll
        for (int m = 0; m < 4; ++m)
#pragma unroll
          for (int n = 0; n < 4; ++n)
            acc[m][n] = __builtin_amdgcn_mfma_f32_16x16x32_bf16(af[m], bfv[n], acc[m][n], 0, 0, 0);
        __builtin_amdgcn_s_setprio(0);
      }
    }

    if (blockIdx.y >= 16) {
      // ---- V epilogue: LDS-bounce transpose (block-uniform branch) ----
      unsigned short* Vlds = smem;             // 32 KB
      __syncthreads();
#pragma unroll
      for (int m = 0; m < 4; ++m)
#pragma unroll
        for (int n = 0; n < 4; ++n)
#pragma unroll
          for (int i = 0; i < 4; ++i) {
            const int rp = wr + m * 16 + kq * 4 + i;
            const int cp = wc + n * 16 + fr;
            Vlds[cp * 128 + (((rp >> 3) ^ (cp & 7)) << 3) + (rp & 7)] = f2bf(acc[m][n][i]);
          }
      __syncthreads();
      const int cp = tid >> 1, half = tid & 1;
      const int b = bm >> 11;
      const int h = ((bn - 2048) >> 6) + (cp >> 6);
      const int d = cp & 63;
      unsigned short* dst =
          v_out + ((size_t)((b * 16 + h) * 64 + d)) * 2048 + (bm & 2047) + half * 64;
#pragma unroll
      for (int s = 0; s < 8; ++s) {
        const int slot = (half * 8 + s) ^ (cp & 7);
        *(sh8*)(dst + s * 8) = *(const sh8*)&Vlds[cp * 128 + slot * 8];
      }
      return;
    }

    // ---- Q/K epilogue: direct contiguous stores ----
#pragma unroll
    for (int m = 0; m < 4; ++m)
#pragma unroll
      for (int n = 0; n < 4; ++n)
#pragma unroll
        for (int i = 0; i < 4; ++i) {
          const int r = bm + wr + m * 16 + kq * 4 + i;
          const int c = bn + wc + n * 16 + fr;
          const float val = acc[m][n][i];
          const int b = r >> 11, nidx = r & 2047;
          const int rem = c & 1023;
          const int h = rem >> 6, d = rem & 63;
          const size_t off = ((size_t)((b * 16 + h) * 2048 + nidx)) * 64 + d;
          if (blockIdx.y < 8) q_out[off] = f2bf(val * 0.18033688f);
          else                k_out[off] = f2bf(val);
        }
  } else {
    // ---- r7 4-deep issue-before-barrier pipeline, counted vmcnt (BK=32) ----
    unsigned short* As = smem;            // 4 x [128][32]
    unsigned short* Bs = smem + 16384;    // 4 x [128][32]
    const int r16 = lane >> 2;
    const int srcsl = (lane & 3) ^ ((r16 >> 1) & 3);
    const int rb0 = wave * 32, rb1 = wave * 32 + 16;
    const int rsl = (kq ^ ((fr >> 1) & 3)) * 8;
    const int nT = K >> 5;
#define GSTAGE(g)                                                                            \
    {                                                                                        \
      const int _b = ((g) & 3) * 4096;                                                       \
      const int _k0 = (g) * 32;                                                              \
      glds16(&A[(size_t)(bm + rb0 + r16) * K + _k0 + srcsl * 8], &As[_b + rb0 * 32]);        \
      glds16(&A[(size_t)(bm + rb1 + r16) * K + _k0 + srcsl * 8], &As[_b + rb1 * 32]);        \
      glds16(&Bt[(size_t)(bn + rb0 + r16) * K + _k0 + srcsl * 8], &Bs[_b + rb0 * 32]);       \
      glds16(&Bt[(size_t)(bn + rb1 + r16) * K + _k0 + srcsl * 8], &Bs[_b + rb1 * 32]);       \
    }
    GSTAGE(0);
    GSTAGE(1);
    for (int j = 0; j < nT; ++j) {
      const int buf = (j & 3) * 4096;
      if (j + 2 < nT) {
        GSTAGE(j + 2);
        asm volatile("s_waitcnt vmcnt(8)" ::: "memory");
      } else if (j + 1 < nT) {
        asm volatile("s_waitcnt vmcnt(4)" ::: "memory");
      } else {
        asm volatile("s_waitcnt vmcnt(0)" ::: "memory");
      }
      __builtin_amdgcn_s_barrier();

      bf8v af[4], bfv[4];
#pragma unroll
      for (int m = 0; m < 4; ++m)
        af[m] = __builtin_bit_cast(bf8v, *(const sh8*)&As[buf + (wr + m * 16 + fr) * 32 + rsl]);
#pragma unroll
      for (int n = 0; n < 4; ++n)
        bfv[n] = __builtin_bit_cast(bf8v, *(const sh8*)&Bs[buf + (wc + n * 16 + fr) * 32 + rsl]);
      __builtin_amdgcn_s_setprio(1);
#pragma unroll
      for (int m = 0; m < 4; ++m)
#pragma unroll
        for (int n = 0; n < 4; ++n)
          acc[m][n] = __builtin_amdgcn_mfma_f32_16x16x32_bf16(af[m], bfv[n], acc[m][n], 0, 0, 0);
      __builtin_amdgcn_s_setprio(0);
    }
#undef GSTAGE

#pragma unroll
    for (int m = 0; m < 4; ++m)
#pragma unroll
      for (int n = 0; n < 4; ++n)
#pragma unroll
        for (int i = 0; i < 4; ++i) {
          const int r = bm + wr + m * 16 + kq * 4 + i;
          const int c = bn + wc + n * 16 + fr;
          c_out[(size_t)r * N + c] = acc[m][n][i] + bias[c];
        }
  }
}

// ---------------- causal flash attention: swapped QK^T, UN-PAIRED q-tiles ----
// 1024 blocks (one 128-row q-tile each), 2 KV buffers (32 KB) -> 4 blocks/CU,
// stage-AFTER-barrier (WAR-safe with 2 buffers; prefetch spans one ~900cyc body).
// Q/K: [bh][2048][64] bf16 (Q pre-scaled by 0.125*log2e). Vt: [bh][64][2048]. O: [B*2048][1024].
// 4 waves x 32 q-rows. Long-tiles-first within XCD chunk.
__global__ __launch_bounds__(256, 4) void attn_kernel(
    const unsigned short* __restrict__ Q, const unsigned short* __restrict__ Kg,
    const unsigned short* __restrict__ Vtg, unsigned short* __restrict__ O) {
  __shared__ alignas(16) unsigned short Ks[2][64 * 64];
  __shared__ alignas(16) unsigned short Vts[2][64 * 64];
  const int tid = threadIdx.x;
  const int lane = tid & 63;
  const int w = tid >> 6;
  const int q31 = lane & 31, hi = lane >> 5;
  const int sw = (lane & 7) << 3;
  // XCD-aware bijective swizzle (nwg=1024): 8 bh per 128-block chunk, long-first
  const int wg = (blockIdx.x & 7) * 128 + (blockIdx.x >> 3);
  const int bh = wg >> 4;
  const int qt = 15 - (wg & 15);
  const unsigned short* Qb = Q + (size_t)bh * (2048 * 64);
  const unsigned short* Kb = Kg + (size_t)bh * (2048 * 64);
  const unsigned short* Vtb = Vtg + (size_t)bh * (64 * 2048);
  const int q0w = qt * 128 + w * 32;

  // Q B-fragments: lane holds Q[q0w+q31][8hi + 16dk + t]
  bf8v qf[4];
#pragma unroll
  for (int dk = 0; dk < 4; ++dk)
    qf[dk] = __builtin_bit_cast(bf8v, *(const sh8*)&Qb[(size_t)(q0w + q31) * 64 + 8 * hi + 16 * dk]);

  f16v o0 = {}, o1 = {};
  float m_i = -1e30f, l_i = 0.f;

  const int r8 = lane >> 3;
  const int gslot = (lane & 7) ^ r8;
  const int rb0 = w * 16, rb1 = w * 16 + 8;

#define STAGE(g)                                                                              \
  {                                                                                           \
    const int _b = (g) & 1;                                                                   \
    glds16(&Kb[(size_t)((g) * 64 + rb0 + r8) * 64 + gslot * 8], &Ks[_b][rb0 * 64]);           \
    glds16(&Kb[(size_t)((g) * 64 + rb1 + r8) * 64 + gslot * 8], &Ks[_b][rb1 * 64]);           \
    glds16(&Vtb[(size_t)(rb0 + r8) * 2048 + (g) * 64 + gslot * 8], &Vts[_b][rb0 * 64]);       \
    glds16(&Vtb[(size_t)(rb1 + r8) * 2048 + (g) * 64 + gslot * 8], &Vts[_b][rb1 * 64]);       \
  }

  const int nT = 2 * qt + 2;
  STAGE(0);

  for (int j = 0; j < nT; ++j) {
    const int buf = j & 1;
    asm volatile("s_waitcnt vmcnt(0)" ::: "memory");   // stage(j) landed (my wave's loads)
    __builtin_amdgcn_s_barrier();                      // all waves' loads landed; body(j-1) done
    if (j + 1 < nT) STAGE(j + 1);                      // overwrites buf (j-1)&1: readers done

    // ---- QK^T (swapped): S^T[k][q], 8 MFMAs ----
    f16v s0 = {}, s1 = {};
    __builtin_amdgcn_s_setprio(1);
#pragma unroll
    for (int dk = 0; dk < 4; ++dk) {
      const int col = (8 * hi + 16 * dk) ^ sw;
      const bf8v k0 = __builtin_bit_cast(bf8v, *(const sh8*)&Ks[buf][q31 * 64 + col]);
      const bf8v k1 = __builtin_bit_cast(bf8v, *(const sh8*)&Ks[buf][(32 + q31) * 64 + col]);
      s0 = __builtin_amdgcn_mfma_f32_32x32x16_bf16(k0, qf[dk], s0, 0, 0, 0);
      s1 = __builtin_amdgcn_mfma_f32_32x32x16_bf16(k1, qf[dk], s1, 0, 0, 0);
    }
    __builtin_amdgcn_s_setprio(0);

    const int qg = q0w + q31;
    if (j * 64 + 63 > q0w) {   // diagonal region
#pragma unroll
      for (int r = 0; r < 16; ++r) {
        const int kl = j * 64 + (r & 3) + 8 * (r >> 2) + 4 * hi;
        if (kl > qg) s0[r] = -1e30f;
        if (kl + 32 > qg) s1[r] = -1e30f;
      }
    }

    float mx = -1e30f;
#pragma unroll
    for (int r = 0; r < 16; ++r) mx = fmaxf(mx, fmaxf(s0[r], s1[r]));
    mx = fmaxf(mx, __shfl_xor(mx, 32));

    if (!__all(mx - m_i <= 8.f)) {   // defer-max rare path
      const float mn = fmaxf(m_i, mx);
      const float alpha = fast_exp2(m_i - mn);
      m_i = mn;
      l_i *= alpha;
#pragma unroll
      for (int r = 0; r < 16; ++r) {
        const float ar = __shfl(alpha, (r & 3) + 8 * (r >> 2) + 4 * hi);
        o0[r] *= ar;
        o1[r] *= ar;
      }
    }

    float ps = 0.f;
#pragma unroll
    for (int r = 0; r < 16; ++r) {
      s0[r] = fast_exp2(s0[r] - m_i);
      s1[r] = fast_exp2(s1[r] - m_i);
      ps += s0[r] + s1[r];
    }
    ps += __shfl_xor(ps, 32);
    l_i += ps;

    unsigned w0[8], w1[8];
#pragma unroll
    for (int jj = 0; jj < 8; ++jj) {
      asm("v_cvt_pk_bf16_f32 %0, %1, %2" : "=v"(w0[jj]) : "v"(s0[2 * jj]), "v"(s0[2 * jj + 1]));
      asm("v_cvt_pk_bf16_f32 %0, %1, %2" : "=v"(w1[jj]) : "v"(s1[2 * jj]), "v"(s1[2 * jj + 1]));
    }

#pragma unroll
    for (int ks = 0; ks < 4; ++ks) {
      const int j0 = 4 * (ks & 1);
      unsigned x0 = (ks < 2 ? w0[j0 + 0] : w1[j0 + 0]);
      unsigned y0 = (ks < 2 ? w0[j0 + 2] : w1[j0 + 2]);
      unsigned x1 = (ks < 2 ? w0[j0 + 1] : w1[j0 + 1]);
      unsigned y1 = (ks < 2 ? w0[j0 + 3] : w1[j0 + 3]);
      asm("v_permlane32_swap_b32 %0, %1" : "+v"(x0), "+v"(y0));
      asm("v_permlane32_swap_b32 %0, %1" : "+v"(x1), "+v"(y1));
      u4v pw;
      pw[0] = x0; pw[1] = x1; pw[2] = y0; pw[3] = y1;
      const bf8v pa = __builtin_bit_cast(bf8v, pw);

      const int colv = (8 * hi + 16 * ks) ^ sw;
      const bf8v vf0 = __builtin_bit_cast(bf8v, *(const sh8*)&Vts[buf][q31 * 64 + colv]);
      const bf8v vf1 = __builtin_bit_cast(bf8v, *(const sh8*)&Vts[buf][(32 + q31) * 64 + colv]);
      __builtin_amdgcn_s_setprio(1);
      o0 = __builtin_amdgcn_mfma_f32_32x32x16_bf16(pa, vf0, o0, 0, 0, 0);
      o1 = __builtin_amdgcn_mfma_f32_32x32x16_bf16(pa, vf1, o1, 0, 0, 0);
      __builtin_amdgcn_s_setprio(0);
    }
  }
#undef STAGE

  // ---- epilogue ----
  const int b = bh >> 4, h = bh & 15;
  const float rl = 1.f / l_i;
#pragma unroll
  for (int r = 0; r < 16; ++r) {
    const int cr = (r & 3) + 8 * (r >> 2) + 4 * hi;
    const float lr = __shfl(rl, cr);
    const size_t base = ((size_t)(b * 2048 + q0w + cr)) * 1024 + h * 64 + q31;
    O[base] = f2bf(o0[r] * lr);
    O[base + 32] = f2bf(o1[r] * lr);
  }
}

extern "C" void kernel_launch(void* const* d_in, const int* in_sizes, int n_in,
                              void* d_out, int out_size, void* d_ws, size_t ws_size,
                              hipStream_t stream) {
  const float* x      = (const float*)d_in[0];
  const float* qkv_w  = (const float*)d_in[1];
  const float* proj_w = (const float*)d_in[2];
  const float* proj_b = (const float*)d_in[3];
  float* out = (float*)d_out;

  unsigned short* ws = (unsigned short*)d_ws;
  const size_t NE = (size_t)8192 * 1024;
  unsigned short* xb     = ws;                            // x bf16; reused as attn out
  unsigned short* wqkvT  = xb + NE;                       // [3072][1024]
  unsigned short* wprojT = wqkvT + (size_t)3072 * 1024;   // [1024][1024]
  unsigned short* qb     = wprojT + (size_t)1024 * 1024;  // [64][2048][64]
  unsigned short* kb     = qb + NE;                       // [64][2048][64]
  unsigned short* vt     = kb + NE;                       // [64][64][2048] (transposed V)
  unsigned short* ab     = xb;

  cast_kernel<<<8192, 256, 0, stream>>>(x, xb);
  transpose_cast_kernel<<<dim3(96, 32), dim3(32, 8), 0, stream>>>(qkv_w, wqkvT, 1024, 3072);
  transpose_cast_kernel<<<dim3(32, 32), dim3(32, 8), 0, stream>>>(proj_w, wprojT, 1024, 1024);

  gemm_bf16_kernel<0><<<dim3(64, 24), 256, 0, stream>>>(
      xb, wqkvT, 8192, 3072, 1024, qb, kb, vt, nullptr, nullptr);

  attn_kernel<<<1024, 256, 0, stream>>>(qb, kb, vt, ab);

  gemm_bf16_kernel<1><<<dim3(64, 8), 256, 0, stream>>>(
      ab, wprojT, 8192, 1024, 1024, nullptr, nullptr, nullptr, proj_b, out);
}

// Round 21
// 169.091 us; speedup vs baseline: 1.1608x; 1.1608x over previous
//
#include <hip/hip_runtime.h>

typedef __attribute__((ext_vector_type(8))) short sh8;
typedef __attribute__((ext_vector_type(8))) __bf16 bf8v;
typedef __attribute__((ext_vector_type(4))) float f4v;
typedef __attribute__((ext_vector_type(16))) float f16v;
typedef __attribute__((ext_vector_type(4))) unsigned u4v;

__device__ __forceinline__ float fast_exp2(float x) { return __builtin_amdgcn_exp2f(x); }

__device__ __forceinline__ unsigned short f2bf(float f) {
  unsigned u = __builtin_bit_cast(unsigned, f);
  u += 0x7fffu + ((u >> 16) & 1u);
  return (unsigned short)(u >> 16);
}
__device__ __forceinline__ float bf2f(unsigned short h) {
  unsigned u = ((unsigned)h) << 16;
  return __builtin_bit_cast(float, u);
}

// async global->LDS, 16B per lane; LDS dest = wave-uniform base + lane*16
__device__ __forceinline__ void glds16(const unsigned short* g, unsigned short* l) {
  __builtin_amdgcn_global_load_lds((const __attribute__((address_space(1))) void*)g,
                                   (__attribute__((address_space(3))) void*)l, 16, 0, 0);
}

// ---------------- cast x -> bf16 (vectorized) ----------------
__global__ __launch_bounds__(256) void cast_kernel(const float* __restrict__ in,
                                                   unsigned short* __restrict__ out) {
  const int idx = (blockIdx.x * 256 + threadIdx.x) * 4;
  const float4 v = *(const float4*)(in + idx);
  ushort4 o;
  o.x = f2bf(v.x); o.y = f2bf(v.y); o.z = f2bf(v.z); o.w = f2bf(v.w);
  *(ushort4*)(out + idx) = o;
}

// ---------------- transpose + cast weights: in[R][C] -> out[C][R] bf16 ----------------
__global__ __launch_bounds__(256) void transpose_cast_kernel(const float* __restrict__ in,
                                                             unsigned short* __restrict__ out,
                                                             int R, int C) {
  __shared__ float tile[32][33];
  const int c0 = blockIdx.x * 32, r0 = blockIdx.y * 32;
  const int tx = threadIdx.x, ty = threadIdx.y;
#pragma unroll
  for (int i = 0; i < 4; ++i)
    tile[ty + 8 * i][tx] = in[(size_t)(r0 + ty + 8 * i) * C + c0 + tx];
  __syncthreads();
#pragma unroll
  for (int i = 0; i < 4; ++i)
    out[(size_t)(c0 + ty + 8 * i) * R + r0 + tx] = f2bf(tile[tx][ty + 8 * i]);
}

// ------- bf16 MFMA GEMM with per-MODE loop structure (byte-identical to r18):
// MODE 0 (QKV): m97 single-buffer loop, BK=64 (32 KB LDS, 4 blocks/CU).
//   Q/K: direct contiguous stores; V: LDS-bounce transpose -> vt[bh][64][2048].
// MODE 1 (proj, 512 blocks): r7 4-deep issue-before-barrier counted-vmcnt pipeline (BK=32).
template <int MODE>
__global__ __launch_bounds__(256, MODE == 0 ? 4 : 2) void gemm_bf16_kernel(
    const unsigned short* __restrict__ A,
    const unsigned short* __restrict__ Bt,
    int M, int N, int K,
    unsigned short* __restrict__ q_out, unsigned short* __restrict__ k_out,
    unsigned short* __restrict__ v_out,
    const float* __restrict__ bias, float* __restrict__ c_out) {
  constexpr int SMEM_SH = (MODE == 0) ? (128 * 128) : (2 * 4 * 128 * 32);
  __shared__ alignas(16) unsigned short smem[SMEM_SH];
  const int tid = threadIdx.x;
  const int lane = tid & 63;
  const int wave = tid >> 6;
  const int wr = (wave >> 1) * 64;
  const int wc = (wave & 1) * 64;
  const int bm = blockIdx.x * 128;
  const int bn = blockIdx.y * 128;
  const int fr = lane & 15;
  const int kq = lane >> 4;

  f4v acc[4][4] = {};

  if constexpr (MODE == 0) {
    // ---- m97 single-buffer loop, BK=64 ----
    unsigned short* As = smem;          // [128][64]
    unsigned short* Bs = smem + 8192;   // [128][64]
    const int srow = lane >> 3;                 // 0..7
    const int sslot = (lane & 7) ^ srow;        // pre-swizzled source slot (row&7 == srow)
    const int nT = K >> 6;                      // 16 for K=1024
    for (int j = 0; j < nT; ++j) {
      const int k0 = j * 64;
      __syncthreads();
#pragma unroll
      for (int c = 0; c < 4; ++c) {
        const int rowbase = wave * 32 + c * 8;
        glds16(&A[(size_t)(bm + rowbase + srow) * K + k0 + sslot * 8], &As[rowbase * 64]);
        glds16(&Bt[(size_t)(bn + rowbase + srow) * K + k0 + sslot * 8], &Bs[rowbase * 64]);
      }
      __syncthreads();

#pragma unroll
      for (int h = 0; h < 2; ++h) {
        bf8v af[4], bfv[4];
        const int rsl = (((h << 2) | kq) ^ (fr & 7)) * 8;
#pragma unroll
        for (int m = 0; m < 4; ++m)
          af[m] = __builtin_bit_cast(bf8v, *(const sh8*)&As[(wr + m * 16 + fr) * 64 + rsl]);
#pragma unroll
        for (int n = 0; n < 4; ++n)
          bfv[n] = __builtin_bit_cast(bf8v, *(const sh8*)&Bs[(wc + n * 16 + fr) * 64 + rsl]);
        __builtin_amdgcn_s_setprio(1);
#pragma unroll
        for (int m = 0; m < 4; ++m)
#pragma unroll
          for (int n = 0; n < 4; ++n)
            acc[m][n] = __builtin_amdgcn_mfma_f32_16x16x32_bf16(af[m], bfv[n], acc[m][n], 0, 0, 0);
        __builtin_amdgcn_s_setprio(0);
      }
    }

    if (blockIdx.y >= 16) {
      // ---- V epilogue: LDS-bounce transpose (block-uniform branch) ----
      unsigned short* Vlds = smem;             // 32 KB
      __syncthreads();
#pragma unroll
      for (int m = 0; m < 4; ++m)
#pragma unroll
        for (int n = 0; n < 4; ++n)
#pragma unroll
          for (int i = 0; i < 4; ++i) {
            const int rp = wr + m * 16 + kq * 4 + i;
            const int cp = wc + n * 16 + fr;
            Vlds[cp * 128 + (((rp >> 3) ^ (cp & 7)) << 3) + (rp & 7)] = f2bf(acc[m][n][i]);
          }
      __syncthreads();
      const int cp = tid >> 1, half = tid & 1;
      const int b = bm >> 11;
      const int h = ((bn - 2048) >> 6) + (cp >> 6);
      const int d = cp & 63;
      unsigned short* dst =
          v_out + ((size_t)((b * 16 + h) * 64 + d)) * 2048 + (bm & 2047) + half * 64;
#pragma unroll
      for (int s = 0; s < 8; ++s) {
        const int slot = (half * 8 + s) ^ (cp & 7);
        *(sh8*)(dst + s * 8) = *(const sh8*)&Vlds[cp * 128 + slot * 8];
      }
      return;
    }

    // ---- Q/K epilogue: direct contiguous stores ----
#pragma unroll
    for (int m = 0; m < 4; ++m)
#pragma unroll
      for (int n = 0; n < 4; ++n)
#pragma unroll
        for (int i = 0; i < 4; ++i) {
          const int r = bm + wr + m * 16 + kq * 4 + i;
          const int c = bn + wc + n * 16 + fr;
          const float val = acc[m][n][i];
          const int b = r >> 11, nidx = r & 2047;
          const int rem = c & 1023;
          const int h = rem >> 6, d = rem & 63;
          const size_t off = ((size_t)((b * 16 + h) * 2048 + nidx)) * 64 + d;
          if (blockIdx.y < 8) q_out[off] = f2bf(val * 0.18033688f);
          else                k_out[off] = f2bf(val);
        }
  } else {
    // ---- r7 4-deep issue-before-barrier pipeline, counted vmcnt (BK=32) ----
    unsigned short* As = smem;            // 4 x [128][32]
    unsigned short* Bs = smem + 16384;    // 4 x [128][32]
    const int r16 = lane >> 2;
    const int srcsl = (lane & 3) ^ ((r16 >> 1) & 3);
    const int rb0 = wave * 32, rb1 = wave * 32 + 16;
    const int rsl = (kq ^ ((fr >> 1) & 3)) * 8;
    const int nT = K >> 5;
#define GSTAGE(g)                                                                            \
    {                                                                                        \
      const int _b = ((g) & 3) * 4096;                                                       \
      const int _k0 = (g) * 32;                                                              \
      glds16(&A[(size_t)(bm + rb0 + r16) * K + _k0 + srcsl * 8], &As[_b + rb0 * 32]);        \
      glds16(&A[(size_t)(bm + rb1 + r16) * K + _k0 + srcsl * 8], &As[_b + rb1 * 32]);        \
      glds16(&Bt[(size_t)(bn + rb0 + r16) * K + _k0 + srcsl * 8], &Bs[_b + rb0 * 32]);       \
      glds16(&Bt[(size_t)(bn + rb1 + r16) * K + _k0 + srcsl * 8], &Bs[_b + rb1 * 32]);       \
    }
    GSTAGE(0);
    GSTAGE(1);
    for (int j = 0; j < nT; ++j) {
      const int buf = (j & 3) * 4096;
      if (j + 2 < nT) {
        GSTAGE(j + 2);
        asm volatile("s_waitcnt vmcnt(8)" ::: "memory");
      } else if (j + 1 < nT) {
        asm volatile("s_waitcnt vmcnt(4)" ::: "memory");
      } else {
        asm volatile("s_waitcnt vmcnt(0)" ::: "memory");
      }
      __builtin_amdgcn_s_barrier();

      bf8v af[4], bfv[4];
#pragma unroll
      for (int m = 0; m < 4; ++m)
        af[m] = __builtin_bit_cast(bf8v, *(const sh8*)&As[buf + (wr + m * 16 + fr) * 32 + rsl]);
#pragma unroll
      for (int n = 0; n < 4; ++n)
        bfv[n] = __builtin_bit_cast(bf8v, *(const sh8*)&Bs[buf + (wc + n * 16 + fr) * 32 + rsl]);
      __builtin_amdgcn_s_setprio(1);
#pragma unroll
      for (int m = 0; m < 4; ++m)
#pragma unroll
        for (int n = 0; n < 4; ++n)
          acc[m][n] = __builtin_amdgcn_mfma_f32_16x16x32_bf16(af[m], bfv[n], acc[m][n], 0, 0, 0);
      __builtin_amdgcn_s_setprio(0);
    }
#undef GSTAGE

#pragma unroll
    for (int m = 0; m < 4; ++m)
#pragma unroll
      for (int n = 0; n < 4; ++n)
#pragma unroll
        for (int i = 0; i < 4; ++i) {
          const int r = bm + wr + m * 16 + kq * 4 + i;
          const int c = bn + wc + n * 16 + fr;
          c_out[(size_t)r * N + c] = acc[m][n][i] + bias[c];
        }
  }
}

// ---------------- causal flash attention: swapped QK^T, paired q-tiles, counted vmcnt ----
// (r18 structure with defer-max softmax; max/sum reductions restructured as balanced
//  trees — same values, ~5x shorter serial VALU chain per tile.)
// Q/K: [bh][2048][64] bf16 (Q pre-scaled by 0.125*log2e). Vt: [bh][64][2048]. O: [B*2048][1024].
// 512 blocks; block = (bh, pair): q-tiles qtA=pair, qtB=15-pair sharing one KV stream.
// 4 waves x 32 q-rows per q-tile. 4-deep LDS buffers, prefetch depth 2, vmcnt(8), raw barrier.
__global__ __launch_bounds__(256, 2) void attn_kernel(
    const unsigned short* __restrict__ Q, const unsigned short* __restrict__ Kg,
    const unsigned short* __restrict__ Vtg, unsigned short* __restrict__ O) {
  __shared__ alignas(16) unsigned short Ks[4][64 * 64];
  __shared__ alignas(16) unsigned short Vts[4][64 * 64];
  const int tid = threadIdx.x;
  const int lane = tid & 63;
  const int w = tid >> 6;
  const int q31 = lane & 31, hi = lane >> 5;
  const int sw = (lane & 7) << 3;
  // XCD-aware bijective swizzle (nwg=512): 8 bh per 64-block chunk
  const int wg = (blockIdx.x & 7) * 64 + (blockIdx.x >> 3);
  const int bh = wg >> 3;
  const int pair = wg & 7;
  const int qtA = pair, qtB = 15 - pair;
  const unsigned short* Qb = Q + (size_t)bh * (2048 * 64);
  const unsigned short* Kb = Kg + (size_t)bh * (2048 * 64);
  const unsigned short* Vtb = Vtg + (size_t)bh * (64 * 2048);
  const int q0wA = qtA * 128 + w * 32;
  const int q0wB = qtB * 128 + w * 32;

  // Q B-fragments for both q-tiles: lane holds Q[q0w+q31][8hi + 16dk + t]
  bf8v qfA[4], qfB[4];
#pragma unroll
  for (int dk = 0; dk < 4; ++dk) {
    qfA[dk] = __builtin_bit_cast(bf8v, *(const sh8*)&Qb[(size_t)(q0wA + q31) * 64 + 8 * hi + 16 * dk]);
    qfB[dk] = __builtin_bit_cast(bf8v, *(const sh8*)&Qb[(size_t)(q0wB + q31) * 64 + 8 * hi + 16 * dk]);
  }

  f16v oA0 = {}, oA1 = {}, oB0 = {}, oB1 = {};
  float mA = -1e30f, lA = 0.f, mB = -1e30f, lB = 0.f;

  const int r8 = lane >> 3;
  const int gslot = (lane & 7) ^ r8;
  const int rb0 = w * 16, rb1 = w * 16 + 8;

#define STAGE(g)                                                                              \
  {                                                                                           \
    const int _b = (g) & 3;                                                                   \
    glds16(&Kb[(size_t)((g) * 64 + rb0 + r8) * 64 + gslot * 8], &Ks[_b][rb0 * 64]);           \
    glds16(&Kb[(size_t)((g) * 64 + rb1 + r8) * 64 + gslot * 8], &Ks[_b][rb1 * 64]);           \
    glds16(&Vtb[(size_t)(rb0 + r8) * 2048 + (g) * 64 + gslot * 8], &Vts[_b][rb0 * 64]);       \
    glds16(&Vtb[(size_t)(rb1 + r8) * 2048 + (g) * 64 + gslot * 8], &Vts[_b][rb1 * 64]);       \
  }

  // one KV-tile body for one q-tile (all state by reference -> static regs)
  auto body = [&](int j, int buf, int q0w, bf8v (&qf)[4], f16v& o0, f16v& o1,
                  float& m_i, float& l_i) {
    f16v s0 = {}, s1 = {};
    __builtin_amdgcn_s_setprio(1);
#pragma unroll
    for (int dk = 0; dk < 4; ++dk) {
      const int col = (8 * hi + 16 * dk) ^ sw;
      const bf8v k0 = __builtin_bit_cast(bf8v, *(const sh8*)&Ks[buf][q31 * 64 + col]);
      const bf8v k1 = __builtin_bit_cast(bf8v, *(const sh8*)&Ks[buf][(32 + q31) * 64 + col]);
      s0 = __builtin_amdgcn_mfma_f32_32x32x16_bf16(k0, qf[dk], s0, 0, 0, 0);
      s1 = __builtin_amdgcn_mfma_f32_32x32x16_bf16(k1, qf[dk], s1, 0, 0, 0);
    }
    __builtin_amdgcn_s_setprio(0);

    const int qg = q0w + q31;
    if (j * 64 + 63 > q0w) {   // diagonal region
#pragma unroll
      for (int r = 0; r < 16; ++r) {
        const int kl = j * 64 + (r & 3) + 8 * (r >> 2) + 4 * hi;
        if (kl > qg) s0[r] = -1e30f;
        if (kl + 32 > qg) s1[r] = -1e30f;
      }
    }

    // ---- balanced-tree row max (depth 5 instead of 32-deep chain) ----
    float t[16];
#pragma unroll
    for (int r = 0; r < 16; ++r) t[r] = fmaxf(s0[r], s1[r]);
#pragma unroll
    for (int off = 8; off; off >>= 1)
#pragma unroll
      for (int i = 0; i < 8; ++i)
        if (i < off) t[i] = fmaxf(t[i], t[i + off]);
    float mx = fmaxf(t[0], __shfl_xor(t[0], 32));

    if (!__all(mx - m_i <= 8.f)) {   // defer-max rare path
      const float mn = fmaxf(m_i, mx);
      const float alpha = fast_exp2(m_i - mn);
      m_i = mn;
      l_i *= alpha;
#pragma unroll
      for (int r = 0; r < 16; ++r) {
        const float ar = __shfl(alpha, (r & 3) + 8 * (r >> 2) + 4 * hi);
        o0[r] *= ar;
        o1[r] *= ar;
      }
    }

    // ---- P = exp2(S - m); balanced-tree row sum ----
    float u[16];
#pragma unroll
    for (int r = 0; r < 16; ++r) {
      s0[r] = fast_exp2(s0[r] - m_i);
      s1[r] = fast_exp2(s1[r] - m_i);
      u[r] = s0[r] + s1[r];
    }
#pragma unroll
    for (int off = 8; off; off >>= 1)
#pragma unroll
      for (int i = 0; i < 8; ++i)
        if (i < off) u[i] += u[i + off];
    float ps = u[0];
    ps += __shfl_xor(ps, 32);
    l_i += ps;

    unsigned w0[8], w1[8];
#pragma unroll
    for (int jj = 0; jj < 8; ++jj) {
      asm("v_cvt_pk_bf16_f32 %0, %1, %2" : "=v"(w0[jj]) : "v"(s0[2 * jj]), "v"(s0[2 * jj + 1]));
      asm("v_cvt_pk_bf16_f32 %0, %1, %2" : "=v"(w1[jj]) : "v"(s1[2 * jj]), "v"(s1[2 * jj + 1]));
    }

#pragma unroll
    for (int ks = 0; ks < 4; ++ks) {
      const int j0 = 4 * (ks & 1);
      unsigned x0 = (ks < 2 ? w0[j0 + 0] : w1[j0 + 0]);
      unsigned y0 = (ks < 2 ? w0[j0 + 2] : w1[j0 + 2]);
      unsigned x1 = (ks < 2 ? w0[j0 + 1] : w1[j0 + 1]);
      unsigned y1 = (ks < 2 ? w0[j0 + 3] : w1[j0 + 3]);
      asm("v_permlane32_swap_b32 %0, %1" : "+v"(x0), "+v"(y0));
      asm("v_permlane32_swap_b32 %0, %1" : "+v"(x1), "+v"(y1));
      u4v pw;
      pw[0] = x0; pw[1] = x1; pw[2] = y0; pw[3] = y1;
      const bf8v pa = __builtin_bit_cast(bf8v, pw);

      const int colv = (8 * hi + 16 * ks) ^ sw;
      const bf8v vf0 = __builtin_bit_cast(bf8v, *(const sh8*)&Vts[buf][q31 * 64 + colv]);
      const bf8v vf1 = __builtin_bit_cast(bf8v, *(const sh8*)&Vts[buf][(32 + q31) * 64 + colv]);
      __builtin_amdgcn_s_setprio(1);
      o0 = __builtin_amdgcn_mfma_f32_32x32x16_bf16(pa, vf0, o0, 0, 0, 0);
      o1 = __builtin_amdgcn_mfma_f32_32x32x16_bf16(pa, vf1, o1, 0, 0, 0);
      __builtin_amdgcn_s_setprio(0);
    }
  };

  const int b = bh >> 4, h = bh & 15;
  auto epi = [&](int q0w, f16v& o0, f16v& o1, float l_i) {
    const float rl = 1.f / l_i;
#pragma unroll
    for (int r = 0; r < 16; ++r) {
      const int cr = (r & 3) + 8 * (r >> 2) + 4 * hi;
      const float lr = __shfl(rl, cr);
      const size_t base = ((size_t)(b * 2048 + q0w + cr)) * 1024 + h * 64 + q31;
      O[base] = f2bf(o0[r] * lr);
      O[base + 32] = f2bf(o1[r] * lr);
    }
  };

  const int nA = 2 * qtA + 2;        // bodyA tiles
  const int nT = 2 * qtB + 2;        // total KV tiles (B is longer; nT > nA always)

  STAGE(0);
  STAGE(1);

  for (int j = 0; j < nT; ++j) {
    const int buf = j & 3;
    if (j + 2 < nT) {
      STAGE(j + 2);
      asm volatile("s_waitcnt vmcnt(8)" ::: "memory");
    } else if (j + 1 < nT) {
      asm volatile("s_waitcnt vmcnt(4)" ::: "memory");
    } else {
      asm volatile("s_waitcnt vmcnt(0)" ::: "memory");
    }
    __builtin_amdgcn_s_barrier();

    if (j < nA) body(j, buf, q0wA, qfA, oA0, oA1, mA, lA);
    body(j, buf, q0wB, qfB, oB0, oB1, mB, lB);

    if (j == nA - 1) epi(q0wA, oA0, oA1, lA);
  }
#undef STAGE

  epi(q0wB, oB0, oB1, lB);
}

extern "C" void kernel_launch(void* const* d_in, const int* in_sizes, int n_in,
                              void* d_out, int out_size, void* d_ws, size_t ws_size,
                              hipStream_t stream) {
  const float* x      = (const float*)d_in[0];
  const float* qkv_w  = (const float*)d_in[1];
  const float* proj_w = (const float*)d_in[2];
  const float* proj_b = (const float*)d_in[3];
  float* out = (float*)d_out;

  unsigned short* ws = (unsigned short*)d_ws;
  const size_t NE = (size_t)8192 * 1024;
  unsigned short* xb     = ws;                            // x bf16; reused as attn out
  unsigned short* wqkvT  = xb + NE;                       // [3072][1024]
  unsigned short* wprojT = wqkvT + (size_t)3072 * 1024;   // [1024][1024]
  unsigned short* qb     = wprojT + (size_t)1024 * 1024;  // [64][2048][64]
  unsigned short* kb     = qb + NE;                       // [64][2048][64]
  unsigned short* vt     = kb + NE;                       // [64][64][2048] (transposed V)
  unsigned short* ab     = xb;

  cast_kernel<<<8192, 256, 0, stream>>>(x, xb);
  transpose_cast_kernel<<<dim3(96, 32), dim3(32, 8), 0, stream>>>(qkv_w, wqkvT, 1024, 3072);
  transpose_cast_kernel<<<dim3(32, 32), dim3(32, 8), 0, stream>>>(proj_w, wprojT, 1024, 1024);

  gemm_bf16_kernel<0><<<dim3(64, 24), 256, 0, stream>>>(
      xb, wqkvT, 8192, 3072, 1024, qb, kb, vt, nullptr, nullptr);

  attn_kernel<<<512, 256, 0, stream>>>(qb, kb, vt, ab);

  gemm_bf16_kernel<1><<<dim3(64, 8), 256, 0, stream>>>(
      ab, wprojT, 8192, 1024, 1024, nullptr, nullptr, nullptr, proj_b, out);
}